// Round 8
// baseline (65.906 us; speedup 1.0000x reference)
//
#include <hip/hip_runtime.h>

typedef float f32x4 __attribute__((ext_vector_type(4)));
typedef float f32x16 __attribute__((ext_vector_type(16)));
typedef short s16x8 __attribute__((ext_vector_type(8)));
typedef unsigned int u32x2 __attribute__((ext_vector_type(2)));
typedef unsigned int u32x4 __attribute__((ext_vector_type(4)));

#define DEVFN static __device__ __forceinline__

constexpr int S_ = 2048;   // sequence (also group-position count)
constexpr int E_ = 512;    // embed
constexpr int D_ = 8;      // head dim
constexpr int P_ = 64;     // qkv proj dim
// 1/(sqrt(8)*ln2)  : exp(s/sqrt(8)) == exp2(s * C2)
constexpr float C2 = 0.35355339059327373f * 1.4426950408889634f;

// Grouping (reshape trap): reference reshapes (B,S,64)->(64,2048,8) row-major:
// group g = b*8 + (s>>8), position p = (s&255)*8 + head, d = channel&7.

// workspace layout (bytes), ~6.6 MB total
constexpr size_t FLAGA_OFF = 0;                                  // int[256]
constexpr size_t WT_OFF    = 1024;                               // Wt[192][512] bf16
constexpr size_t WUT_OFF   = WT_OFF + (size_t)192 * 512 * 2;     // Wut[512][64] bf16
constexpr size_t QG_OFF    = WUT_OFF + (size_t)512 * 64 * 2;     // Q [64g][2048][8] bf16
constexpr size_t KG_OFF    = QG_OFF + (size_t)64 * 2048 * 8 * 2; // K [64g][2048][8] bf16
constexpr size_t VTG_OFF   = KG_OFF + (size_t)64 * 2048 * 8 * 2; // V^T pi-layout bf16

DEVFN short f2bf(float f) {  // fp32 -> bf16 (RNE)
  unsigned u = __builtin_bit_cast(unsigned, f);
  return (short)((u + 0x7FFFu + ((u >> 16) & 1u)) >> 16);
}

DEVFN unsigned pkbf(float lo, float hi) {  // packed bf16 pair
  unsigned r;
  asm("v_cvt_pk_bf16_f32 %0, %1, %2" : "=v"(r) : "v"(lo), "v"(hi));
  return r;
}

DEVFN float fexp2(float x) {  // raw v_exp_f32 (args bounded; no OCML fixups)
#if __has_builtin(__builtin_amdgcn_exp2f)
  return __builtin_amdgcn_exp2f(x);
#else
  return exp2f(x);
#endif
}

DEVFN f32x16 mfma32(s16x8 a, s16x8 b, f32x16 c) {
  return __builtin_amdgcn_mfma_f32_32x32x16_bf16(a, b, c, 0, 0, 0);
}

DEVFN f32x16 zero16() {
  f32x16 z = {0,0,0,0,0,0,0,0,0,0,0,0,0,0,0,0};
  return z;
}

// ---------------- kernel 0: weight prep (bf16 transposed) + mask-zero flags ------
__global__ __launch_bounds__(256)
void prep_kernel(const float* __restrict__ Wq, const float* __restrict__ Wk,
                 const float* __restrict__ Wv, const float* __restrict__ Wu,
                 const float* __restrict__ maskm, short* __restrict__ WT,
                 short* __restrict__ WUT, int* __restrict__ flagA)
{
  int bid = blockIdx.x, tid = threadIdx.x;
  if (bid < 48) {                       // Wt[n][k] = W[k][n], n<192 k<512
    int base = (bid * 256 + tid) * 8;
#pragma unroll
    for (int j = 0; j < 8; ++j) {
      int idx = base + j;
      int n = idx >> 9, k = idx & 511;
      const float* W = (n < 64) ? Wq : ((n < 128) ? Wk : Wv);
      WT[idx] = f2bf(W[k * 64 + (n & 63)]);
    }
  } else if (bid < 56) {                // Wut[n][k] = Wu[k][n], n<512 k<64
    int base = ((bid - 48) * 256 + tid) * 16;
#pragma unroll
    for (int j = 0; j < 16; ++j) {
      int idx = base + j;
      int n = idx >> 6, k = idx & 63;
      WUT[idx] = f2bf(Wu[k * 512 + n]);
    }
  } else {                              // mask all-zero check -> flagA[bid-56]
    __shared__ int bf_;
    if (tid == 0) bf_ = 0;
    __syncthreads();
    const f32x4* m4 = (const f32x4*)maskm;
    int base = (bid - 56) * 4096;
    unsigned any = 0;
#pragma unroll
    for (int i = 0; i < 16; ++i) {
      f32x4 v = m4[base + i * 256 + tid];
      any |= __builtin_bit_cast(unsigned, v[0]) | __builtin_bit_cast(unsigned, v[1])
           | __builtin_bit_cast(unsigned, v[2]) | __builtin_bit_cast(unsigned, v[3]);
    }
    if (any != 0) atomicOr(&bf_, 1);    // LDS atomic; -0.0 nonzero: safe (slow path)
    __syncthreads();
    if (tid == 0) flagA[bid - 56] = bf_; // plain store, no global init needed
  }
}

// ---------------- kernel 1: QKV projection  x[16384,512] @ W -> bf16 group layouts
// Q pre-scaled by C2. V^T written pi-permuted [g][t][d][slot] so attn's PV
// A-operand key order matches the QK C-layout key order (no P transpose needed).
__global__ __launch_bounds__(384)
void proj_kernel(const float* __restrict__ x, const short* __restrict__ WT,
                 const float* __restrict__ bq, const float* __restrict__ bk,
                 const float* __restrict__ bv, short* __restrict__ QG,
                 short* __restrict__ KG, short* __restrict__ VTG)
{
  __shared__ short xl[32 * 520];        // x tile bf16, row stride 520 (bank pad)
  int tid = threadIdx.x;
  int mb = blockIdx.x * 32;
  for (int i = tid; i < 32 * 128; i += 384) {
    int row = i >> 7, c4 = i & 127;
    f32x4 v = *(const f32x4*)(x + (size_t)(mb + row) * E_ + c4 * 4);
    u32x2 w;
    w[0] = pkbf(v[0], v[1]);
    w[1] = pkbf(v[2], v[3]);
    *(u32x2*)(&xl[row * 520 + c4 * 4]) = w;
  }
  __syncthreads();
  int lane = tid & 63, wvi = tid >> 6;  // 6 waves, each an n-strip of 32
  int l31 = lane & 31, h = lane >> 5;
  int nstrip = wvi * 32;
  f32x16 acc = zero16();
#pragma unroll 4
  for (int kk = 0; kk < E_; kk += 16) { // C^T = Wt * x^T
    s16x8 af = *(const s16x8*)(WT + (size_t)(nstrip + l31) * E_ + kk + 8 * h);
    s16x8 bf = *(const s16x8*)(&xl[l31 * 520 + kk + 8 * h]);
    acc = mfma32(af, bf, acc);
  }
  int token = mb + l31;
  int bidx = token >> 11, s = token & 2047;
  int gg = bidx * 8 + (s >> 8);         // group = batch*8 + chunk
#pragma unroll
  for (int i = 0; i < 4; ++i) {
    int n0 = nstrip + 8 * i + 4 * h;    // 4 consecutive n per reg quad
    int proj = n0 >> 6;
    int wi = n0 & 63;
    int head = wi >> 3, db = wi & 7;    // db = 4h
    const float* bias = (proj == 0) ? bq : ((proj == 1) ? bk : bv);
    float sc = (proj == 0) ? C2 : 1.0f; // fold softmax scale into Q
    float f0 = (acc[4*i+0] + bias[wi+0]) * sc;
    float f1 = (acc[4*i+1] + bias[wi+1]) * sc;
    float f2 = (acc[4*i+2] + bias[wi+2]) * sc;
    float f3 = (acc[4*i+3] + bias[wi+3]) * sc;
    int p = ((s & 255) << 3) + head;    // group position = (s%256)*8 + head
    if (proj == 2) {                    // V^T: [g][t=p>>4][d][sigma(p&15)]
      int k16 = p & 15;
      int slot = (k16 & 3) + ((k16 >> 2) & 1) * 8 + (k16 >> 3) * 4;
      size_t vb = (size_t)gg * (S_ * D_) + (size_t)(p >> 4) * 128 + slot;
      VTG[vb + (db+0)*16] = f2bf(f0);
      VTG[vb + (db+1)*16] = f2bf(f1);
      VTG[vb + (db+2)*16] = f2bf(f2);
      VTG[vb + (db+3)*16] = f2bf(f3);
    } else {
      short* dst = (proj == 0) ? QG : KG;
      u32x2 o;
      o[0] = pkbf(f0, f1);
      o[1] = pkbf(f2, f3);
      *(u32x2*)(dst + ((size_t)gg * S_ + p) * D_ + db) = o;
    }
  }
}

// paired (64-key) pipelined tile body. kf0/kf1 hold the CURRENT pair's K frags
// on entry; when PREFETCH, they are reloaded for the NEXT pair during exp work.
#define PAIR_BODY(kb, PREFETCH, USEMASK)                                \
  {                                                                     \
    f32x16 st0 = mfma32(kf0, qf, zero16());                             \
    f32x16 st1 = mfma32(kf1, qf, zero16());                             \
    s16x8 va0a = *(const s16x8*)vptr;                                   \
    s16x8 va0b = *(const s16x8*)(vptr + 144);                           \
    s16x8 va1a = *(const s16x8*)(vptr + 288);                           \
    s16x8 va1b = *(const s16x8*)(vptr + 432);                           \
    vptr += 576;                                                        \
    if (PREFETCH) {                                                     \
      kf0 = *(const s16x8*)kptr;                                        \
      kf1 = *(const s16x8*)(kptr + kstride);                            \
      kptr += 2 * kstride;                                              \
    }                                                                   \
    float p0[16], p1[16];                                               \
    _Pragma("unroll")                                                   \
    for (int r = 0; r < 16; ++r) {                                      \
      float s0 = st0[r], s1 = st1[r];                                   \
      if (USEMASK) {                                                    \
        int key = (kb) + (r & 3) + 8 * (r >> 2) + 4 * h;                \
        s0 += maskm[(size_t)q * S_ + key] * C2;                         \
        s1 += maskm[(size_t)q * S_ + key + 32] * C2;                    \
      }                                                                 \
      p0[r] = fexp2(s0);                                                \
      p1[r] = fexp2(s1);                                                \
    }                                                                   \
    u32x4 b00, b01, b10, b11;                                           \
    b00[0] = pkbf(p0[0],  p0[1]);  b00[1] = pkbf(p0[2],  p0[3]);        \
    b00[2] = pkbf(p0[4],  p0[5]);  b00[3] = pkbf(p0[6],  p0[7]);        \
    b01[0] = pkbf(p0[8],  p0[9]);  b01[1] = pkbf(p0[10], p0[11]);       \
    b01[2] = pkbf(p0[12], p0[13]); b01[3] = pkbf(p0[14], p0[15]);       \
    b10[0] = pkbf(p1[0],  p1[1]);  b10[1] = pkbf(p1[2],  p1[3]);        \
    b10[2] = pkbf(p1[4],  p1[5]);  b10[3] = pkbf(p1[6],  p1[7]);        \
    b11[0] = pkbf(p1[8],  p1[9]);  b11[1] = pkbf(p1[10], p1[11]);       \
    b11[2] = pkbf(p1[12], p1[13]); b11[3] = pkbf(p1[14], p1[15]);       \
    __builtin_amdgcn_s_setprio(1);                                      \
    acc = mfma32(va0a, __builtin_bit_cast(s16x8, b00), acc);            \
    acc = mfma32(va0b, __builtin_bit_cast(s16x8, b01), acc);            \
    acc = mfma32(va1a, __builtin_bit_cast(s16x8, b10), acc);            \
    acc = mfma32(va1b, __builtin_bit_cast(s16x8, b11), acc);            \
    __builtin_amdgcn_s_setprio(0);                                      \
  }

// ---------------- kernel 2: fused attention + output GEMM ------------------------
// Per block: one (group g, 256-q chunk) = complete attn rows for 32 consecutive
// tokens; epilogue computes out[32][512] = ATTtile @ Wu + bu directly.
__global__ __launch_bounds__(512, 4)
void attn_kernel(const short* __restrict__ QG, const short* __restrict__ KG,
                 const short* __restrict__ VTG, const float* __restrict__ maskm,
                 const int* __restrict__ flagA, const short* __restrict__ WUT,
                 const float* __restrict__ bu, float* __restrict__ out)
{
  __shared__ short K_lds[S_ * D_];          // [key][8]            32KB
  __shared__ short V_lds[128 * 9 * 16];     // [t][d(8)+ones][16]  36KB
  __shared__ short A_lds[32 * 68];          // attn tile [32 tok][64+pad] 4.25KB
  __shared__ short Z_lds[8];                // zero block (h=1 K reads)
  __shared__ int   sm_flag;
  int bid = blockIdx.x;
  int swz = (bid & 7) * 64 + (bid >> 3);    // XCD-chunked swizzle (512 = 8*64)
  int g  = swz >> 3;
  int qb = (swz & 7) * 256;
  int tid = threadIdx.x;
  {
    const u32x4* ks = (const u32x4*)(KG  + (size_t)g * (S_ * D_));
    const u32x4* vs = (const u32x4*)(VTG + (size_t)g * (S_ * D_));
    u32x4* kd = (u32x4*)K_lds;
#pragma unroll
    for (int it = 0; it < 4; ++it) {
      int i = tid + it * 512;
      kd[i] = ks[i];
      u32x4 v = vs[i];
      int t = i >> 4, rem = i & 15;         // rem = d*2 + half
      *(u32x4*)(&V_lds[t * 144 + rem * 8]) = v;
    }
    if (tid < 8) Z_lds[tid] = 0;
    unsigned one2 = 0x3F803F80u;            // ones row d=8 (denominator)
    u32x2 o2; o2[0] = one2; o2[1] = one2;
    int t = tid >> 2, qr = tid & 3;
    *(u32x2*)(&V_lds[t * 144 + 128 + qr * 4]) = o2;
    if (tid < 64) {                         // gather mask flags (256 ints)
      const u32x4* fa4 = (const u32x4*)flagA;
      u32x4 f = fa4[tid];
      unsigned anyf = f[0] | f[1] | f[2] | f[3];
      unsigned long long bb = __ballot(anyf != 0);
      if (tid == 0) sm_flag = (bb != 0ull) ? 1 : 0;
    }
  }
  __syncthreads();

  int lane = tid & 63, wvi = tid >> 6;      // 8 waves, each a 32-q strip
  int l31 = lane & 31, h = lane >> 5;
  int q = qb + wvi * 32 + l31;              // this lane's q position (C column)
  bool hi = (h != 0);
  int dcl = (l31 < 8) ? l31 : 8;            // V row (clamped to ones row)
  s16x8 zero8 = {0,0,0,0,0,0,0,0};

  s16x8 qf = hi ? zero8
                : *(const s16x8*)(QG + ((size_t)g * S_ + q) * D_);
  const short* kptr = hi ? Z_lds : &K_lds[l31 * 8];
  int kstride = hi ? 0 : 32 * 8;            // shorts per 32-key tile
  const short* vptr = &V_lds[dcl * 16 + 8 * h];
  f32x16 acc = zero16();
  bool usemask = (sm_flag != 0);

  // prologue: load pair 0's K fragments
  s16x8 kf0 = *(const s16x8*)kptr;
  s16x8 kf1 = *(const s16x8*)(kptr + kstride);
  kptr += 2 * kstride;

  if (!usemask) {
    for (int kb = 0; kb < S_ - 64; kb += 64) PAIR_BODY(kb, true, false)
    PAIR_BODY(S_ - 64, false, false)
  } else {
    for (int kb = 0; kb < S_ - 64; kb += 64) PAIR_BODY(kb, true, true)
    PAIR_BODY(S_ - 64, false, true)
  }
  // denominator: C row 8 (ones row) = acc[4] of h=0 lanes; share via shfl
  float d0 = acc[4];
  float dp = __shfl_xor(d0, 32, 64);
  float den = hi ? dp : d0;
  float inv = __builtin_amdgcn_rcpf(den);
  u32x2 o;
  o[0] = pkbf(acc[0] * inv, acc[1] * inv);
  o[1] = pkbf(acc[2] * inv, acc[3] * inv);
  // attn tile -> LDS: token-local row = (q-qb)>>3, channel = (q&7)*8 + d
  int local = wvi * 4 + (l31 >> 3);
  int col = (l31 & 7) * 8 + 4 * h;
  *(u32x2*)(&A_lds[local * 68 + col]) = o;
  __syncthreads();
  // out GEMM: out[32 tok][512] = A @ Wu + bu; wave wvi owns n-strip [wvi*64,+64)
  int nb = wvi * 64;
  f32x16 accA = zero16(), accB = zero16();
#pragma unroll
  for (int kk = 0; kk < 64; kk += 16) {
    s16x8 af  = *(const s16x8*)(&A_lds[l31 * 68 + kk + 8 * h]);
    s16x8 bfA = *(const s16x8*)(WUT + (size_t)(nb + l31) * P_ + kk + 8 * h);
    s16x8 bfB = *(const s16x8*)(WUT + (size_t)(nb + 32 + l31) * P_ + kk + 8 * h);
    accA = mfma32(af, bfA, accA);
    accB = mfma32(af, bfB, accB);
  }
  size_t token_base = (size_t)(g >> 3) * S_ + (g & 7) * 256 + (qb >> 3);
  size_t obase = token_base * E_;
  int nA = nb + l31, nB = nb + 32 + l31;
  float biasA = bu[nA], biasB = bu[nB];
#pragma unroll
  for (int r = 0; r < 16; ++r) {
    int m = (r & 3) + 8 * (r >> 2) + 4 * h;
    out[obase + (size_t)m * E_ + nA] = accA[r] + biasA;
    out[obase + (size_t)m * E_ + nB] = accB[r] + biasB;
  }
}

extern "C" void kernel_launch(void* const* d_in, const int* in_sizes, int n_in,
                              void* d_out, int out_size, void* d_ws, size_t ws_size,
                              hipStream_t stream) {
  const float* x     = (const float*)d_in[0];
  const float* maskm = (const float*)d_in[1];
  const float* Wq    = (const float*)d_in[2];
  const float* bq    = (const float*)d_in[3];
  const float* Wk    = (const float*)d_in[4];
  const float* bk    = (const float*)d_in[5];
  const float* Wv    = (const float*)d_in[6];
  const float* bv    = (const float*)d_in[7];
  const float* Wu    = (const float*)d_in[8];
  const float* bu    = (const float*)d_in[9];
  float* out = (float*)d_out;
  char* ws = (char*)d_ws;
  int*   flagA = (int*)(ws + FLAGA_OFF);
  short* WT    = (short*)(ws + WT_OFF);
  short* WUT   = (short*)(ws + WUT_OFF);
  short* QG    = (short*)(ws + QG_OFF);
  short* KG    = (short*)(ws + KG_OFF);
  short* VTG   = (short*)(ws + VTG_OFF);

  prep_kernel<<<312, 256, 0, stream>>>(Wq, Wk, Wv, Wu, maskm, WT, WUT, flagA);
  proj_kernel<<<512, 384, 0, stream>>>(x, WT, bq, bk, bv, QG, KG, VTG);
  attn_kernel<<<512, 512, 0, stream>>>(QG, KG, VTG, maskm, flagA, WUT, bu, out);
}